// Round 10
// baseline (328.783 us; speedup 1.0000x reference)
//
#include <hip/hip_runtime.h>
#include <hip/hip_bf16.h>

typedef __attribute__((ext_vector_type(8))) short bf16x8;
typedef __attribute__((ext_vector_type(4))) float f32x4;
typedef __attribute__((ext_vector_type(4))) int i32x4;
typedef __attribute__((ext_vector_type(2))) unsigned int u32x2;
typedef __attribute__((ext_vector_type(4))) unsigned int u32x4;

// RNE fp32 -> bf16 bits (inputs finite; no NaN handling needed)
__device__ __forceinline__ unsigned int f2bf(float f) {
    union { float f; unsigned int u; } v; v.f = f;
    unsigned int u = v.u;
    u += 0x7FFFu + ((u >> 16) & 1u);
    return u >> 16;
}

__device__ __forceinline__ void gl_lds16(const void* gptr, void* lptr) {
    __builtin_amdgcn_global_load_lds(
        (const __attribute__((address_space(1))) unsigned int*)gptr,
        (__attribute__((address_space(3))) unsigned int*)lptr, 16, 0, 0);
}

// ---------- pre-pass converts ----------
__global__ __launch_bounds__(256) void convert_x_kernel(
    const float* __restrict__ x, unsigned short* __restrict__ xb, long long n8)
{
    long long i = (long long)blockIdx.x * blockDim.x + threadIdx.x;
    const long long stride = (long long)gridDim.x * blockDim.x;
    for (; i < n8; i += stride) {
        const f32x4* p = (const f32x4*)(x + i * 8);
        f32x4 v0 = p[0], v1 = p[1];
        u32x4 q;
        q[0] = f2bf(v0[0]) | (f2bf(v0[1]) << 16);
        q[1] = f2bf(v0[2]) | (f2bf(v0[3]) << 16);
        q[2] = f2bf(v1[0]) | (f2bf(v1[1]) << 16);
        q[3] = f2bf(v1[2]) | (f2bf(v1[3]) << 16);
        *(u32x4*)(xb + i * 8) = q;
    }
}

__global__ __launch_bounds__(256) void convert_w_kernel(
    const int* __restrict__ w, unsigned short* __restrict__ wb, long long n8)
{
    long long i = (long long)blockIdx.x * blockDim.x + threadIdx.x;
    const long long stride = (long long)gridDim.x * blockDim.x;
    for (; i < n8; i += stride) {
        const i32x4* p = (const i32x4*)(w + i * 8);
        i32x4 v0 = p[0], v1 = p[1];
        u32x4 q;   // int8 values are exact in bf16
        q[0] = f2bf((float)v0[0]) | (f2bf((float)v0[1]) << 16);
        q[1] = f2bf((float)v0[2]) | (f2bf((float)v0[3]) << 16);
        q[2] = f2bf((float)v1[0]) | (f2bf((float)v1[1]) << 16);
        q[3] = f2bf((float)v1[2]) | (f2bf((float)v1[3]) << 16);
        *(u32x4*)(wb + i * 8) = q;
    }
}

// ---------- 256x128 / BK=32 pipelined GEMM, 2 blocks/CU (TLP play) ----------
// 256 thr = 4 waves (2M x 2N); per-wave out 128x64; acc 8x4 f32x4.
// LDS 64 KB/block: A tribuf 3x16KB @ {0,16K,32K}; B dbuf 2x8KB @ {48K,56K}
//   -> TWO blocks co-resident per CU (128 <= 160 KB): independent barrier
//   domains + epilogue/K-loop overlap across blocks (r9 post-mortem: all
//   single-block schedules plateau at ~50% MfmaUtil).
// Tiles are [rows][64B]; stored linearly as [rows/2][128B] ldsrows.
//   logical slot (16B) of ldsrow R: L = (grow&1)*4 + kq; phys = L ^ (R&7).
// Schedule per tile (2 phases), r9-invariant hazards:
//   ph0: stage B(t+1); read a4-7(t); MFMA fm0-3 x b.
//   ph1: stage A(t+2); vmcnt(4); B3 barrier (globalize per-wave vmcnt ->
//        tile t+1 fully DMA'd); MFMA fm4-7 x b; prefetch-read a0-3',b'(t+1);
//        END barrier (frees regions for restage).
__global__ __launch_bounds__(256, 2) void gemm256_kernel(
    const unsigned short* __restrict__ A, const unsigned short* __restrict__ Bw,
    const float* __restrict__ wscale, const float* __restrict__ bias,
    float* __restrict__ out, int M, int N, int K)
{
    __shared__ unsigned char lds[65536];
    const int BOFF = 49152;

    const int tid  = threadIdx.x;
    const int lane = tid & 63;
    const int wid  = tid >> 6;
    const int wr   = wid >> 1;   // 0..1 -> 128 output rows each
    const int wc   = wid & 1;    // 0..1 -> 64 output cols each

    const int ntn = N >> 7;
    const int nwg = gridDim.x;
    int bid = blockIdx.x;
    if ((nwg & 7) == 0) {                       // XCD-aware swizzle (T1)
        const int cpx = nwg >> 3;
        bid = (bid & 7) * cpx + (bid >> 3);
    }
    const int bm = bid / ntn;
    const int bn = bid % ntn;
    const int NT = K >> 5;                      // BK = 32

    const char* Abase = (const char*)(A  + (size_t)bm * 256 * K);
    const char* Bbase = (const char*)(Bw + (size_t)bn * 128 * K);
    const size_t rowb = (size_t)K * 2;

    // staging source addressing (rule 21: linear LDS dest, pre-swizzled src).
    // thread t, pass p -> LDS bytes p*4096 + t*16; ldsrow = p*32 + (t>>3),
    // phys slot = t&7, logical slot slog = (t&7) ^ ((t>>3)&7);
    // global row = p*64 + 2*(t>>3) + (slog>>2); col byte = (slog&3)*16.
    const int slog = (tid & 7) ^ ((tid >> 3) & 7);
    const int sR   = 2 * (tid >> 3) + (slog >> 2);
    const int sC   = (slog & 3) * 16;

    auto stageA = [&](const char* g, char* dst) {     // 256 rows x 64B = 16KB
#pragma unroll
        for (int p = 0; p < 4; ++p)
            gl_lds16(g + (size_t)(p * 64 + sR) * rowb + sC, dst + p * 4096 + tid * 16);
    };
    auto stageB = [&](const char* g, char* dst) {     // 128 rows x 64B = 8KB
#pragma unroll
        for (int p = 0; p < 2; ++p)
            gl_lds16(g + (size_t)(p * 64 + sR) * rowb + sC, dst + p * 4096 + tid * 16);
    };
    auto Ag = [&](int kt) { return Abase + (size_t)kt * 64; };
    auto Bg = [&](int kt) { return Bbase + (size_t)kt * 64; };

    // fragment-read addressing: global row r = base + (lane&15) + f*16,
    // k-quarter q = lane>>4. byte = (r>>1)*128 + (((r&1)*4+q)^((r>>1)&7))*16.
    // per-lane phys slot: aps = ((lane&1)*4 + (lane>>4)) ^ ((lane&15)>>1).
    const int aps   = (((lane & 1) << 2) | (lane >> 4)) ^ ((lane & 15) >> 1);
    const int aBase = (wr * 64 + ((lane & 15) >> 1)) * 128 + aps * 16;
    const int bBase = (wc * 32 + ((lane & 15) >> 1)) * 128 + aps * 16;

    f32x4 acc[8][4];
#pragma unroll
    for (int mi = 0; mi < 8; ++mi)
#pragma unroll
        for (int ni = 0; ni < 4; ++ni)
            acc[mi][ni] = (f32x4){0.f, 0.f, 0.f, 0.f};

    bf16x8 a[4], a4[4], b[4];

    // ---- prologue: A(0)->buf0, B(0)->Bbuf0, A(1)->buf1; tile0 must land ----
    stageA(Ag(0), (char*)lds + 0);
    stageB(Bg(0), (char*)lds + BOFF);
    if (NT > 1) {
        stageA(Ag(1), (char*)lds + 16384);
        asm volatile("s_waitcnt vmcnt(4)" ::: "memory");   // A(1) may stay in flight
    } else {
        asm volatile("s_waitcnt vmcnt(0)" ::: "memory");
    }
    __builtin_amdgcn_sched_barrier(0);
    asm volatile("s_barrier" ::: "memory");
    {
        const char* Al = (const char*)lds;
        const char* Bl = (const char*)lds + BOFF;
#pragma unroll
        for (int fm = 0; fm < 4; ++fm) a[fm] = *(const bf16x8*)(Al + aBase + fm * 1024);
#pragma unroll
        for (int fn = 0; fn < 4; ++fn) b[fn] = *(const bf16x8*)(Bl + bBase + fn * 1024);
    }

    int acur = 0, anxt = 16384, ann = 32768;   // A tribuf rotation
    int bcur = BOFF, both = BOFF + 8192;       // B dbuf

    for (int kt = 0; kt < NT; ++kt) {
        const char* Al = (const char*)lds + acur;

        // ---- ph0: stage B(t+1); read a4-7(t); MFMA fm0-3 x b ----
        if (kt + 1 < NT) stageB(Bg(kt + 1), (char*)lds + both);
#pragma unroll
        for (int fm = 0; fm < 4; ++fm) a4[fm] = *(const bf16x8*)(Al + aBase + (fm + 4) * 1024);
        __builtin_amdgcn_s_setprio(1);
#pragma unroll
        for (int fm = 0; fm < 4; ++fm)
#pragma unroll
            for (int fn = 0; fn < 4; ++fn)
                acc[fm][fn] = __builtin_amdgcn_mfma_f32_16x16x32_bf16(a[fm], b[fn], acc[fm][fn], 0, 0, 0);
        __builtin_amdgcn_s_setprio(0);

        // ---- ph1: stage A(t+2); vmcnt; B3; MFMA fm4-7 x b; prefetch; END ----
        if (kt + 2 < NT) stageA(Ag(kt + 2), (char*)lds + ann);
        if (kt + 1 < NT) {
            if (kt + 2 < NT) { asm volatile("s_waitcnt vmcnt(4)" ::: "memory"); }
            else             { asm volatile("s_waitcnt vmcnt(0)" ::: "memory"); }
            __builtin_amdgcn_sched_barrier(0);
            asm volatile("s_barrier" ::: "memory");          // B3: tile t+1 landed
        }
        __builtin_amdgcn_s_setprio(1);
#pragma unroll
        for (int fm = 0; fm < 4; ++fm)
#pragma unroll
            for (int fn = 0; fn < 4; ++fn)
                acc[fm + 4][fn] = __builtin_amdgcn_mfma_f32_16x16x32_bf16(a4[fm], b[fn], acc[fm + 4][fn], 0, 0, 0);
        __builtin_amdgcn_s_setprio(0);
        if (kt + 1 < NT) {
            const char* nAl = (const char*)lds + anxt;
            const char* nBl = (const char*)lds + both;
#pragma unroll
            for (int fm = 0; fm < 4; ++fm) a[fm] = *(const bf16x8*)(nAl + aBase + fm * 1024);
#pragma unroll
            for (int fn = 0; fn < 4; ++fn) b[fn] = *(const bf16x8*)(nBl + bBase + fn * 1024);
        }
        asm volatile("s_barrier" ::: "memory");              // END: region handoff + swap

        const int at = acur; acur = anxt; anxt = ann; ann = at;
        const int bt = bcur; bcur = both; both = bt;
    }

    // epilogue: out = acc*scale + bias ; C/D layout col=lane&15, row=(lane>>4)*4+i
    const float scale = *wscale;
    const int orow0 = bm * 256 + wr * 128 + ((lane >> 4) << 2);
    const int ocol0 = bn * 128 + wc * 64  + (lane & 15);
#pragma unroll
    for (int fn = 0; fn < 4; ++fn) {
        const int col = ocol0 + 16 * fn;
        const float bb = bias[col];
#pragma unroll
        for (int fm = 0; fm < 8; ++fm) {
            const int row0 = orow0 + 16 * fm;
#pragma unroll
            for (int i = 0; i < 4; ++i)
                out[(size_t)(row0 + i) * N + col] = acc[fm][fn][i] * scale + bb;
        }
    }
}

// ---------- fallback: round-2 fused kernel (passes; used only if ws too small) ----------
__device__ __forceinline__ int swz(int row, int byte_in_row) {
    return row * 128 + (byte_in_row ^ ((row & 7) << 4));
}

__global__ __launch_bounds__(256) void qlinear_fused_kernel(
    const float* __restrict__ X, const int* __restrict__ W,
    const float* __restrict__ wscale, const float* __restrict__ bias,
    float* __restrict__ out, int M, int N, int K)
{
    __shared__ unsigned char smem[32768];

    const int t    = threadIdx.x;
    const int lane = t & 63;
    const int wid  = t >> 6;
    const int wr   = wid >> 1;
    const int wc   = wid & 1;

    const int ntn = N >> 7;
    const int bm  = blockIdx.x / ntn;
    const int bn  = blockIdx.x % ntn;
    const int NT  = K >> 6;

    const float* Ab = X + (size_t)bm * 128 * K;
    const int*   Bb = W + (size_t)bn * 128 * K;

    const int srow = t >> 4, sc4 = t & 15;

    f32x4 av[8];
    i32x4 bv[8];

    auto loadAB = [&](int kt) {
        const float* Ap = Ab + kt * 64 + sc4 * 4;
#pragma unroll
        for (int l = 0; l < 8; ++l)
            av[l] = *(const f32x4*)(Ap + (size_t)(srow + 16 * l) * K);
        const int* Bp = Bb + kt * 64 + sc4 * 4;
#pragma unroll
        for (int l = 0; l < 8; ++l)
            bv[l] = *(const i32x4*)(Bp + (size_t)(srow + 16 * l) * K);
    };

    auto writeAB = [&]() {
#pragma unroll
        for (int l = 0; l < 8; ++l) {
            const int row = srow + 16 * l;
            u32x2 pk;
            pk[0] = f2bf(av[l][0]) | (f2bf(av[l][1]) << 16);
            pk[1] = f2bf(av[l][2]) | (f2bf(av[l][3]) << 16);
            *(u32x2*)(smem + swz(row, sc4 * 8)) = pk;
        }
#pragma unroll
        for (int l = 0; l < 8; ++l) {
            const int row = srow + 16 * l;
            u32x2 pk;
            pk[0] = f2bf((float)bv[l][0]) | (f2bf((float)bv[l][1]) << 16);
            pk[1] = f2bf((float)bv[l][2]) | (f2bf((float)bv[l][3]) << 16);
            *(u32x2*)(smem + 16384 + swz(row, sc4 * 8)) = pk;
        }
    };

    f32x4 acc[4][4];
#pragma unroll
    for (int mi = 0; mi < 4; ++mi)
#pragma unroll
        for (int ni = 0; ni < 4; ++ni)
            acc[mi][ni] = (f32x4){0.f, 0.f, 0.f, 0.f};

    const int kbyte = (lane >> 4) * 16;
    const int afr   = wr * 64 + (lane & 15);
    const int bfr   = wc * 64 + (lane & 15);

    loadAB(0);

    for (int kt = 0; kt < NT; ++kt) {
        writeAB();
        __syncthreads();
        if (kt + 1 < NT) loadAB(kt + 1);
#pragma unroll
        for (int kk = 0; kk < 2; ++kk) {
            bf16x8 a[4], b[4];
#pragma unroll
            for (int mi = 0; mi < 4; ++mi)
                a[mi] = *(const bf16x8*)(smem + swz(afr + 16 * mi, kk * 64 + kbyte));
#pragma unroll
            for (int ni = 0; ni < 4; ++ni)
                b[ni] = *(const bf16x8*)(smem + 16384 + swz(bfr + 16 * ni, kk * 64 + kbyte));
#pragma unroll
            for (int mi = 0; mi < 4; ++mi)
#pragma unroll
                for (int ni = 0; ni < 4; ++ni)
                    acc[mi][ni] = __builtin_amdgcn_mfma_f32_16x16x32_bf16(
                        a[mi], b[ni], acc[mi][ni], 0, 0, 0);
        }
        __syncthreads();
    }

    const float scale = *wscale;
    const int orow0 = bm * 128 + wr * 64 + ((lane >> 4) << 2);
    const int ocol0 = bn * 128 + wc * 64 + (lane & 15);
#pragma unroll
    for (int ni = 0; ni < 4; ++ni) {
        const int col = ocol0 + 16 * ni;
        const float bb = bias[col];
#pragma unroll
        for (int mi = 0; mi < 4; ++mi) {
            const int row0 = orow0 + 16 * mi;
#pragma unroll
            for (int i = 0; i < 4; ++i)
                out[(size_t)(row0 + i) * N + col] = acc[mi][ni][i] * scale + bb;
        }
    }
}

extern "C" void kernel_launch(void* const* d_in, const int* in_sizes, int n_in,
                              void* d_out, int out_size, void* d_ws, size_t ws_size,
                              hipStream_t stream) {
    const float* x      = (const float*)d_in[0];
    const int*   w      = (const int*)d_in[1];      // int inputs arrive as int32
    const float* wscale = (const float*)d_in[2];
    const float* bias   = (const float*)d_in[3];
    float*       out    = (float*)d_out;

    const int DOUT = in_sizes[3];
    const int DIN  = in_sizes[1] / DOUT;
    const int M    = in_sizes[0] / DIN;

    const size_t xb_bytes = (size_t)M * DIN * 2;
    const size_t wb_bytes = (size_t)DOUT * DIN * 2;

    if (ws_size >= xb_bytes + wb_bytes && (M % 256) == 0 && (DOUT % 128) == 0
        && (DIN % 32) == 0 && (DIN / 32) >= 2) {
        unsigned short* xb = (unsigned short*)d_ws;
        unsigned short* wb = (unsigned short*)((char*)d_ws + xb_bytes);

        const long long nx8 = (long long)M * DIN / 8;
        const long long nw8 = (long long)DOUT * DIN / 8;
        convert_x_kernel<<<2048, 256, 0, stream>>>(x, xb, nx8);
        convert_w_kernel<<<2048, 256, 0, stream>>>(w, wb, nw8);

        dim3 grid((M / 256) * (DOUT / 128));
        gemm256_kernel<<<grid, 256, 0, stream>>>(xb, wb, wscale, bias, out, M, DOUT, DIN);
    } else {
        dim3 grid((M / 128) * (DOUT / 128));
        qlinear_fused_kernel<<<grid, 256, 0, stream>>>(x, w, wscale, bias, out, M, DOUT, DIN);
    }
}

// Round 11
// 310.284 us; speedup vs baseline: 1.0596x; 1.0596x over previous
//
#include <hip/hip_runtime.h>
#include <hip/hip_bf16.h>

typedef __attribute__((ext_vector_type(8))) short bf16x8;
typedef __attribute__((ext_vector_type(16))) float f32x16;
typedef __attribute__((ext_vector_type(4))) float f32x4;
typedef __attribute__((ext_vector_type(4))) int i32x4;
typedef __attribute__((ext_vector_type(2))) unsigned int u32x2;
typedef __attribute__((ext_vector_type(4))) unsigned int u32x4;

// RNE fp32 -> bf16 bits (inputs finite; no NaN handling needed)
__device__ __forceinline__ unsigned int f2bf(float f) {
    union { float f; unsigned int u; } v; v.f = f;
    unsigned int u = v.u;
    u += 0x7FFFu + ((u >> 16) & 1u);
    return u >> 16;
}

__device__ __forceinline__ void gl_lds16(const void* gptr, void* lptr) {
    __builtin_amdgcn_global_load_lds(
        (const __attribute__((address_space(1))) unsigned int*)gptr,
        (__attribute__((address_space(3))) unsigned int*)lptr, 16, 0, 0);
}

// ---------- pre-pass converts ----------
__global__ __launch_bounds__(256) void convert_x_kernel(
    const float* __restrict__ x, unsigned short* __restrict__ xb, long long n8)
{
    long long i = (long long)blockIdx.x * blockDim.x + threadIdx.x;
    const long long stride = (long long)gridDim.x * blockDim.x;
    for (; i < n8; i += stride) {
        const f32x4* p = (const f32x4*)(x + i * 8);
        f32x4 v0 = p[0], v1 = p[1];
        u32x4 q;
        q[0] = f2bf(v0[0]) | (f2bf(v0[1]) << 16);
        q[1] = f2bf(v0[2]) | (f2bf(v0[3]) << 16);
        q[2] = f2bf(v1[0]) | (f2bf(v1[1]) << 16);
        q[3] = f2bf(v1[2]) | (f2bf(v1[3]) << 16);
        *(u32x4*)(xb + i * 8) = q;
    }
}

__global__ __launch_bounds__(256) void convert_w_kernel(
    const int* __restrict__ w, unsigned short* __restrict__ wb, long long n8)
{
    long long i = (long long)blockIdx.x * blockDim.x + threadIdx.x;
    const long long stride = (long long)gridDim.x * blockDim.x;
    for (; i < n8; i += stride) {
        const i32x4* p = (const i32x4*)(w + i * 8);
        i32x4 v0 = p[0], v1 = p[1];
        u32x4 q;   // int8 values are exact in bf16
        q[0] = f2bf((float)v0[0]) | (f2bf((float)v0[1]) << 16);
        q[1] = f2bf((float)v0[2]) | (f2bf((float)v0[3]) << 16);
        q[2] = f2bf((float)v1[0]) | (f2bf((float)v1[1]) << 16);
        q[3] = f2bf((float)v1[2]) | (f2bf((float)v1[3]) << 16);
        *(u32x4*)(wb + i * 8) = q;
    }
}

// ---------- 256x256 pipelined GEMM, 32x32x16 MFMA (r9 schedule) ----------
// 512 thr = 8 waves in 4Mx2N; per-wave out 64x128 = 2x4 frags of 32x32.
// MFMA 32x32x16_bf16: 4061 FLOP/cy/CU (m119) vs 3378 for 16x16x32 -> ~17%
// more matrix throughput at identical LDS traffic and acc budget.
// LDS 160KB: A tribuf 3x32KB @ {0,32768,65536}; B dbuf 2x32KB @ {98304,131072}.
// r9-verified schedule: 4 phases/tile (one K-step of 16 each, 8 MFMA + 6
// ds_read_b128); stage rotation p0/p1 -> B(t+1), p2/p3 -> A(t+2) (into
// A(t-1)'s buffer, freed via END(t-1)); vmcnt(4) + B3 barrier at p3
// (globalizes per-wave vmcnt -> tile t+1 fully DMA'd before prefetch-read);
// END barrier closes the tile. 2 barriers/tile, no wave-global lgkmcnt.
// Fragment layouts (HW-validated family): A row=lane&31, k=(lane>>5)*8+j;
// B col=lane&31, same k; C/D col=lane&31, row=(reg&3)+8*(reg>>2)+4*(lane>>5).
__global__ __launch_bounds__(512, 2) void gemm256_kernel(
    const unsigned short* __restrict__ A, const unsigned short* __restrict__ Bw,
    const float* __restrict__ wscale, const float* __restrict__ bias,
    float* __restrict__ out, int M, int N, int K)
{
    __shared__ unsigned char lds[163840];
    const int B0OFF = 98304;

    const int tid  = threadIdx.x;
    const int lane = tid & 63;
    const int wid  = tid >> 6;
    const int wr   = wid >> 1;   // 0..3 -> 64 output rows each
    const int wc   = wid & 1;    // 0..1 -> 128 output cols each

    const int ntn = N >> 8;
    const int nwg = gridDim.x;
    int bid = blockIdx.x;
    if ((nwg & 7) == 0) {                       // XCD-aware swizzle (T1)
        const int cpx = nwg >> 3;
        bid = (bid & 7) * cpx + (bid >> 3);
    }
    const int bm = bid / ntn;
    const int bn = bid % ntn;
    const int NT = K >> 6;

    const char* Abase = (const char*)(A  + (size_t)bm * 256 * K);
    const char* Bbase = (const char*)(Bw + (size_t)bn * 256 * K);
    const size_t rowb = (size_t)K * 2;

    // staging: half-tile = 128 rows x 128B (16KB); 2 gl_lds per thread.
    // Linear LDS dest; source column pre-swizzled (rule 21):
    // LDS(row, physSlot) = global(row, physSlot ^ (row&7)), slots of 16B.
    const int s_colb = (((lane & 7) ^ (lane >> 3)) << 4);
    const int s_rsub = wid * 8 + (lane >> 3);
    const int s_ldso = wid * 1024 + lane * 16;

    auto stageHalf = [&](const char* gRowBase, char* lhalf) {
#pragma unroll
        for (int q = 0; q < 2; ++q)
            gl_lds16(gRowBase + (size_t)(q * 64 + s_rsub) * rowb + s_colb,
                     lhalf + q * 8192 + s_ldso);
    };
    auto Ag = [&](int kt, int h) { return Abase + (size_t)kt * 128 + (size_t)(h * 128) * rowb; };
    auto Bg = [&](int kt, int h) { return Bbase + (size_t)kt * 128 + (size_t)(h * 128) * rowb; };

    // fragment-read addressing (swizzled): row = base + (lane&31) [+32*frag],
    // K-step ks: logical byte = ks*32 + (lane>>5)*16; phys ^= (row&7)<<4.
    const int aBase = (wr * 64  + (lane & 31)) * 128;
    const int bBase = (wc * 128 + (lane & 31)) * 128;
    const int swx = (lane & 7) << 4;
    const int khi = (lane >> 5) * 16;
    const int ksb0 = (0 * 32 + khi) ^ swx;
    const int ksb1 = (1 * 32 + khi) ^ swx;
    const int ksb2 = (2 * 32 + khi) ^ swx;
    const int ksb3 = (3 * 32 + khi) ^ swx;

    f32x16 acc[2][4];
#pragma unroll
    for (int mf = 0; mf < 2; ++mf)
#pragma unroll
        for (int fn = 0; fn < 4; ++fn)
#pragma unroll
            for (int i = 0; i < 16; ++i)
                acc[mf][fn][i] = 0.f;

    bf16x8 aE[2], aO[2], bE[4], bO[4];

    // ---- prologue: A(0)->Abuf0, B(0)->Bbuf0, A(1)->Abuf1; tile0 must land ----
    stageHalf(Ag(0, 0), (char*)lds + 0);
    stageHalf(Ag(0, 1), (char*)lds + 16384);
    stageHalf(Bg(0, 0), (char*)lds + B0OFF);
    stageHalf(Bg(0, 1), (char*)lds + B0OFF + 16384);
    if (NT > 1) {
        stageHalf(Ag(1, 0), (char*)lds + 32768);
        stageHalf(Ag(1, 1), (char*)lds + 32768 + 16384);
        asm volatile("s_waitcnt vmcnt(4)" ::: "memory");   // A(1) may stay in flight
    } else {
        asm volatile("s_waitcnt vmcnt(0)" ::: "memory");
    }
    __builtin_amdgcn_sched_barrier(0);
    asm volatile("s_barrier" ::: "memory");
    // read ks0 of tile 0
    {
        const char* Al = (const char*)lds;
        const char* Bl = (const char*)lds + B0OFF;
#pragma unroll
        for (int mf = 0; mf < 2; ++mf) aE[mf] = *(const bf16x8*)(Al + aBase + mf * 4096 + ksb0);
#pragma unroll
        for (int fn = 0; fn < 4; ++fn) bE[fn] = *(const bf16x8*)(Bl + bBase + fn * 4096 + ksb0);
    }

    int acur = 0, anxt = 32768, ann = 65536;   // A tribuf rotation
    int bcur = B0OFF, both = B0OFF + 32768;    // B dbuf

    for (int kt = 0; kt < NT; ++kt) {
        const char* Al = (const char*)lds + acur;
        const char* Bl = (const char*)lds + bcur;

        // ---- p0: stage B0(t+1); read ks1 -> aO,bO; MFMA ks0 (aE,bE) ----
        if (kt + 1 < NT) stageHalf(Bg(kt + 1, 0), (char*)lds + both);
#pragma unroll
        for (int mf = 0; mf < 2; ++mf) aO[mf] = *(const bf16x8*)(Al + aBase + mf * 4096 + ksb1);
#pragma unroll
        for (int fn = 0; fn < 4; ++fn) bO[fn] = *(const bf16x8*)(Bl + bBase + fn * 4096 + ksb1);
        __builtin_amdgcn_s_setprio(1);
#pragma unroll
        for (int mf = 0; mf < 2; ++mf)
#pragma unroll
            for (int fn = 0; fn < 4; ++fn)
                acc[mf][fn] = __builtin_amdgcn_mfma_f32_32x32x16_bf16(aE[mf], bE[fn], acc[mf][fn], 0, 0, 0);
        __builtin_amdgcn_s_setprio(0);

        // ---- p1: stage B1(t+1); read ks2 -> aE,bE; MFMA ks1 ----
        if (kt + 1 < NT) stageHalf(Bg(kt + 1, 1), (char*)lds + both + 16384);
#pragma unroll
        for (int mf = 0; mf < 2; ++mf) aE[mf] = *(const bf16x8*)(Al + aBase + mf * 4096 + ksb2);
#pragma unroll
        for (int fn = 0; fn < 4; ++fn) bE[fn] = *(const bf16x8*)(Bl + bBase + fn * 4096 + ksb2);
        __builtin_amdgcn_s_setprio(1);
#pragma unroll
        for (int mf = 0; mf < 2; ++mf)
#pragma unroll
            for (int fn = 0; fn < 4; ++fn)
                acc[mf][fn] = __builtin_amdgcn_mfma_f32_32x32x16_bf16(aO[mf], bO[fn], acc[mf][fn], 0, 0, 0);
        __builtin_amdgcn_s_setprio(0);

        // ---- p2: stage A0(t+2); read ks3 -> aO,bO; MFMA ks2 ----
        if (kt + 2 < NT) stageHalf(Ag(kt + 2, 0), (char*)lds + ann);
#pragma unroll
        for (int mf = 0; mf < 2; ++mf) aO[mf] = *(const bf16x8*)(Al + aBase + mf * 4096 + ksb3);
#pragma unroll
        for (int fn = 0; fn < 4; ++fn) bO[fn] = *(const bf16x8*)(Bl + bBase + fn * 4096 + ksb3);
        __builtin_amdgcn_s_setprio(1);
#pragma unroll
        for (int mf = 0; mf < 2; ++mf)
#pragma unroll
            for (int fn = 0; fn < 4; ++fn)
                acc[mf][fn] = __builtin_amdgcn_mfma_f32_32x32x16_bf16(aE[mf], bE[fn], acc[mf][fn], 0, 0, 0);
        __builtin_amdgcn_s_setprio(0);

        // ---- p3: stage A1(t+2); vmcnt(4); B3; read ks0(t+1); MFMA ks3; END ----
        if (kt + 2 < NT) stageHalf(Ag(kt + 2, 1), (char*)lds + ann + 16384);
        if (kt + 1 < NT) {
            if (kt + 2 < NT) { asm volatile("s_waitcnt vmcnt(4)" ::: "memory"); }
            else             { asm volatile("s_waitcnt vmcnt(0)" ::: "memory"); }
            __builtin_amdgcn_sched_barrier(0);
            asm volatile("s_barrier" ::: "memory");          // B3: tile t+1 fully landed
            const char* nAl = (const char*)lds + anxt;
            const char* nBl = (const char*)lds + both;
#pragma unroll
            for (int mf = 0; mf < 2; ++mf) aE[mf] = *(const bf16x8*)(nAl + aBase + mf * 4096 + ksb0);
#pragma unroll
            for (int fn = 0; fn < 4; ++fn) bE[fn] = *(const bf16x8*)(nBl + bBase + fn * 4096 + ksb0);
        }
        __builtin_amdgcn_s_setprio(1);
#pragma unroll
        for (int mf = 0; mf < 2; ++mf)
#pragma unroll
            for (int fn = 0; fn < 4; ++fn)
                acc[mf][fn] = __builtin_amdgcn_mfma_f32_32x32x16_bf16(aO[mf], bO[fn], acc[mf][fn], 0, 0, 0);
        __builtin_amdgcn_s_setprio(0);
        asm volatile("s_barrier" ::: "memory");              // END: region handoff + swap

        const int at = acur; acur = anxt; anxt = ann; ann = at;
        const int bt = bcur; bcur = both; both = bt;
    }

    // epilogue: out = acc*scale + bias
    // C/D 32x32: col = lane&31, row = (reg&3) + 8*(reg>>2) + 4*(lane>>5)
    const float scale = *wscale;
    const int orow0 = bm * 256 + wr * 64  + ((lane >> 5) << 2);
    const int ocol0 = bn * 256 + wc * 128 + (lane & 31);
#pragma unroll
    for (int fn = 0; fn < 4; ++fn) {
        const int col = ocol0 + 32 * fn;
        const float bb = bias[col];
#pragma unroll
        for (int mf = 0; mf < 2; ++mf) {
            const int rb = orow0 + 32 * mf;
#pragma unroll
            for (int r = 0; r < 16; ++r) {
                const int row = rb + ((r >> 2) << 3) + (r & 3);
                out[(size_t)row * N + col] = acc[mf][fn][r] * scale + bb;
            }
        }
    }
}

// ---------- fallback: round-2 fused kernel (passes; used only if ws too small) ----------
__device__ __forceinline__ int swz(int row, int byte_in_row) {
    return row * 128 + (byte_in_row ^ ((row & 7) << 4));
}

__global__ __launch_bounds__(256) void qlinear_fused_kernel(
    const float* __restrict__ X, const int* __restrict__ W,
    const float* __restrict__ wscale, const float* __restrict__ bias,
    float* __restrict__ out, int M, int N, int K)
{
    __shared__ unsigned char smem[32768];

    const int t    = threadIdx.x;
    const int lane = t & 63;
    const int wid  = t >> 6;
    const int wr   = wid >> 1;
    const int wc   = wid & 1;

    const int ntn = N >> 7;
    const int bm  = blockIdx.x / ntn;
    const int bn  = blockIdx.x % ntn;
    const int NT  = K >> 6;

    const float* Ab = X + (size_t)bm * 128 * K;
    const int*   Bb = W + (size_t)bn * 128 * K;

    const int srow = t >> 4, sc4 = t & 15;

    f32x4 av[8];
    i32x4 bv[8];

    auto loadAB = [&](int kt) {
        const float* Ap = Ab + kt * 64 + sc4 * 4;
#pragma unroll
        for (int l = 0; l < 8; ++l)
            av[l] = *(const f32x4*)(Ap + (size_t)(srow + 16 * l) * K);
        const int* Bp = Bb + kt * 64 + sc4 * 4;
#pragma unroll
        for (int l = 0; l < 8; ++l)
            bv[l] = *(const i32x4*)(Bp + (size_t)(srow + 16 * l) * K);
    };

    auto writeAB = [&]() {
#pragma unroll
        for (int l = 0; l < 8; ++l) {
            const int row = srow + 16 * l;
            u32x2 pk;
            pk[0] = f2bf(av[l][0]) | (f2bf(av[l][1]) << 16);
            pk[1] = f2bf(av[l][2]) | (f2bf(av[l][3]) << 16);
            *(u32x2*)(smem + swz(row, sc4 * 8)) = pk;
        }
#pragma unroll
        for (int l = 0; l < 8; ++l) {
            const int row = srow + 16 * l;
            u32x2 pk;
            pk[0] = f2bf((float)bv[l][0]) | (f2bf((float)bv[l][1]) << 16);
            pk[1] = f2bf((float)bv[l][2]) | (f2bf((float)bv[l][3]) << 16);
            *(u32x2*)(smem + 16384 + swz(row, sc4 * 8)) = pk;
        }
    };

    f32x4 acc[4][4];
#pragma unroll
    for (int mi = 0; mi < 4; ++mi)
#pragma unroll
        for (int ni = 0; ni < 4; ++ni)
            acc[mi][ni] = (f32x4){0.f, 0.f, 0.f, 0.f};

    const int kbyte = (lane >> 4) * 16;
    const int afr   = wr * 64 + (lane & 15);
    const int bfr   = wc * 64 + (lane & 15);

    loadAB(0);

    for (int kt = 0; kt < NT; ++kt) {
        writeAB();
        __syncthreads();
        if (kt + 1 < NT) loadAB(kt + 1);
#pragma unroll
        for (int kk = 0; kk < 2; ++kk) {
            bf16x8 a[4], b[4];
#pragma unroll
            for (int mi = 0; mi < 4; ++mi)
                a[mi] = *(const bf16x8*)(smem + swz(afr + 16 * mi, kk * 64 + kbyte));
#pragma unroll
            for (int ni = 0; ni < 4; ++ni)
                b[ni] = *(const bf16x8*)(smem + 16384 + swz(bfr + 16 * ni, kk * 64 + kbyte));
#pragma unroll
            for (int mi = 0; mi < 4; ++mi)
#pragma unroll
                for (int ni = 0; ni < 4; ++ni)
                    acc[mi][ni] = __builtin_amdgcn_mfma_f32_16x16x32_bf16(
                        a[mi], b[ni], acc[mi][ni], 0, 0, 0);
        }
        __syncthreads();
    }

    const float scale = *wscale;
    const int orow0 = bm * 128 + wr * 64 + ((lane >> 4) << 2);
    const int ocol0 = bn * 128 + wc * 64 + (lane & 15);
#pragma unroll
    for (int ni = 0; ni < 4; ++ni) {
        const int col = ocol0 + 16 * ni;
        const float bb = bias[col];
#pragma unroll
        for (int mi = 0; mi < 4; ++mi) {
            const int row0 = orow0 + 16 * mi;
#pragma unroll
            for (int i = 0; i < 4; ++i)
                out[(size_t)(row0 + i) * N + col] = acc[mi][ni][i] * scale + bb;
        }
    }
}

extern "C" void kernel_launch(void* const* d_in, const int* in_sizes, int n_in,
                              void* d_out, int out_size, void* d_ws, size_t ws_size,
                              hipStream_t stream) {
    const float* x      = (const float*)d_in[0];
    const int*   w      = (const int*)d_in[1];      // int inputs arrive as int32
    const float* wscale = (const float*)d_in[2];
    const float* bias   = (const float*)d_in[3];
    float*       out    = (float*)d_out;

    const int DOUT = in_sizes[3];
    const int DIN  = in_sizes[1] / DOUT;
    const int M    = in_sizes[0] / DIN;

    const size_t xb_bytes = (size_t)M * DIN * 2;
    const size_t wb_bytes = (size_t)DOUT * DIN * 2;

    if (ws_size >= xb_bytes + wb_bytes && (M % 256) == 0 && (DOUT % 256) == 0
        && (DIN % 64) == 0 && (DIN / 64) >= 2) {
        unsigned short* xb = (unsigned short*)d_ws;
        unsigned short* wb = (unsigned short*)((char*)d_ws + xb_bytes);

        const long long nx8 = (long long)M * DIN / 8;
        const long long nw8 = (long long)DOUT * DIN / 8;
        convert_x_kernel<<<2048, 256, 0, stream>>>(x, xb, nx8);
        convert_w_kernel<<<2048, 256, 0, stream>>>(w, wb, nw8);

        dim3 grid((M / 256) * (DOUT / 256));
        gemm256_kernel<<<grid, 512, 0, stream>>>(xb, wb, wscale, bias, out, M, DOUT, DIN);
    } else {
        dim3 grid((M / 128) * (DOUT / 128));
        qlinear_fused_kernel<<<grid, 256, 0, stream>>>(x, w, wscale, bias, out, M, DOUT, DIN);
    }
}

// Round 12
// 298.140 us; speedup vs baseline: 1.1028x; 1.0407x over previous
//
#include <hip/hip_runtime.h>
#include <hip/hip_bf16.h>

typedef __attribute__((ext_vector_type(8))) short bf16x8;
typedef __attribute__((ext_vector_type(4))) float f32x4;
typedef __attribute__((ext_vector_type(4))) int i32x4;
typedef __attribute__((ext_vector_type(2))) unsigned int u32x2;
typedef __attribute__((ext_vector_type(4))) unsigned int u32x4;

// RNE fp32 -> bf16 bits (inputs finite; no NaN handling needed)
__device__ __forceinline__ unsigned int f2bf(float f) {
    union { float f; unsigned int u; } v; v.f = f;
    unsigned int u = v.u;
    u += 0x7FFFu + ((u >> 16) & 1u);
    return u >> 16;
}

__device__ __forceinline__ void gl_lds16(const void* gptr, void* lptr) {
    __builtin_amdgcn_global_load_lds(
        (const __attribute__((address_space(1))) unsigned int*)gptr,
        (__attribute__((address_space(3))) unsigned int*)lptr, 16, 0, 0);
}

// ---------- pre-pass converts ----------
__global__ __launch_bounds__(256) void convert_x_kernel(
    const float* __restrict__ x, unsigned short* __restrict__ xb, long long n8)
{
    long long i = (long long)blockIdx.x * blockDim.x + threadIdx.x;
    const long long stride = (long long)gridDim.x * blockDim.x;
    for (; i < n8; i += stride) {
        const f32x4* p = (const f32x4*)(x + i * 8);
        f32x4 v0 = p[0], v1 = p[1];
        u32x4 q;
        q[0] = f2bf(v0[0]) | (f2bf(v0[1]) << 16);
        q[1] = f2bf(v0[2]) | (f2bf(v0[3]) << 16);
        q[2] = f2bf(v1[0]) | (f2bf(v1[1]) << 16);
        q[3] = f2bf(v1[2]) | (f2bf(v1[3]) << 16);
        *(u32x4*)(xb + i * 8) = q;
    }
}

__global__ __launch_bounds__(256) void convert_w_kernel(
    const int* __restrict__ w, unsigned short* __restrict__ wb, long long n8)
{
    long long i = (long long)blockIdx.x * blockDim.x + threadIdx.x;
    const long long stride = (long long)gridDim.x * blockDim.x;
    for (; i < n8; i += stride) {
        const i32x4* p = (const i32x4*)(w + i * 8);
        i32x4 v0 = p[0], v1 = p[1];
        u32x4 q;   // int8 values are exact in bf16
        q[0] = f2bf((float)v0[0]) | (f2bf((float)v0[1]) << 16);
        q[1] = f2bf((float)v0[2]) | (f2bf((float)v0[3]) << 16);
        q[2] = f2bf((float)v1[0]) | (f2bf((float)v1[1]) << 16);
        q[3] = f2bf((float)v1[2]) | (f2bf((float)v1[3]) << 16);
        *(u32x4*)(wb + i * 8) = q;
    }
}

// ---------- 256x256 per-phase-interleaved GEMM (m201-style, 16x16x32) ----------
// 512 thr = 8 waves in 2M x 4N (m201 geometry); per-wave out 128x64; acc[8][4].
// LDS 160KB: A tribuf 3x32KB @ {0,32768,65536}; B dbuf 2x32KB @ {98304,131072}.
// 4 phases/tile, each: {ds_read this phase's frags (4 or 8 x b128) | stage 1
// half-tile | barrier | setprio(1) 16 MFMA setprio(0) | barrier}  (m196: this
// fine interleave is the lever; m218: counted vmcnt is what makes it pay).
// Stage rotation during tile t: p0->B0(t+1), p1->B1(t+1) (B dbuf), p2->A0(t+2),
// p3->A1(t+2) (A tribuf slot holding A(t-1), long dead).
// ONE counted wait/tile: vmcnt(4) at p3-end (drains B(t+1)+A(t+1), leaves
// A(t+2)'s 4 loads in flight = 3 half-tiles ahead); the END barrier after it
// globalizes per-wave vmcnt across waves (r6 lesson). Never vmcnt(0) mid-loop.
// Swizzle/staging identical to r9 (measured 0 bank conflicts).
__global__ __launch_bounds__(512, 2) void gemm256_kernel(
    const unsigned short* __restrict__ A, const unsigned short* __restrict__ Bw,
    const float* __restrict__ wscale, const float* __restrict__ bias,
    float* __restrict__ out, int M, int N, int K)
{
    __shared__ unsigned char lds[163840];
    const int B0OFF = 98304;

    const int tid  = threadIdx.x;
    const int lane = tid & 63;
    const int wid  = tid >> 6;
    const int wr   = wid >> 2;   // 0..1 -> 128 output rows each
    const int wc   = wid & 3;    // 0..3 -> 64 output cols each

    const int ntn = N >> 8;
    const int nwg = gridDim.x;
    int bid = blockIdx.x;
    if ((nwg & 7) == 0) {                       // XCD-aware swizzle (T1)
        const int cpx = nwg >> 3;
        bid = (bid & 7) * cpx + (bid >> 3);
    }
    const int bm = bid / ntn;
    const int bn = bid % ntn;
    const int NT = K >> 6;

    const char* Abase = (const char*)(A  + (size_t)bm * 256 * K);
    const char* Bbase = (const char*)(Bw + (size_t)bn * 256 * K);
    const size_t rowb = (size_t)K * 2;

    // staging: half-tile = 128 rows x 128B (16KB); 2 gl_lds per thread.
    // Linear LDS dest; source column pre-swizzled (rule 21).
    const int s_colb = (((lane & 7) ^ (lane >> 3)) << 4);
    const int s_rsub = wid * 8 + (lane >> 3);
    const int s_ldso = wid * 1024 + lane * 16;

    auto stageHalf = [&](const char* gRowBase, char* lhalf) {
#pragma unroll
        for (int q = 0; q < 2; ++q)
            gl_lds16(gRowBase + (size_t)(q * 64 + s_rsub) * rowb + s_colb,
                     lhalf + q * 8192 + s_ldso);
    };
    auto Ag = [&](int kt, int h) { return Abase + (size_t)kt * 128 + (size_t)(h * 128) * rowb; };
    auto Bg = [&](int kt, int h) { return Bbase + (size_t)kt * 128 + (size_t)(h * 128) * rowb; };

    // fragment-read addressing (swizzled; same family as r9 -> 0 conflicts)
    const int aBase = (wr * 128 + (lane & 15)) * 128;   // wave's 128 A rows
    const int bBase = (wc * 64  + (lane & 15)) * 128;   // wave's 64 B rows
    const int csw0 = (((lane >> 4) * 16))      ^ ((lane & 7) << 4);
    const int csw1 = (((lane >> 4) * 16) + 64) ^ ((lane & 7) << 4);

    f32x4 acc[8][4];
#pragma unroll
    for (int mi = 0; mi < 8; ++mi)
#pragma unroll
        for (int ni = 0; ni < 4; ++ni)
            acc[mi][ni] = (f32x4){0.f, 0.f, 0.f, 0.f};

    bf16x8 ra[4], rb[4];

    // ---- prologue: A(0)->Atri0, B(0)->Bbuf0, A(1)->Atri1; vmcnt(4) ----
    stageHalf(Ag(0, 0), (char*)lds + 0);
    stageHalf(Ag(0, 1), (char*)lds + 16384);
    stageHalf(Bg(0, 0), (char*)lds + B0OFF);
    stageHalf(Bg(0, 1), (char*)lds + B0OFF + 16384);
    if (NT > 1) {
        stageHalf(Ag(1, 0), (char*)lds + 32768);
        stageHalf(Ag(1, 1), (char*)lds + 32768 + 16384);
        asm volatile("s_waitcnt vmcnt(4)" ::: "memory");   // A(1) may stay in flight
    } else {
        asm volatile("s_waitcnt vmcnt(0)" ::: "memory");
    }
    __builtin_amdgcn_sched_barrier(0);
    asm volatile("s_barrier" ::: "memory");

    int acur = 0, anxt = 32768, ann = 65536;   // A tribuf rotation
    int bcur = B0OFF, both = B0OFF + 32768;    // B dbuf

    for (int kt = 0; kt < NT; ++kt) {
        const char* Al = (const char*)lds + acur;
        const char* Bl = (const char*)lds + bcur;
        char* Bs  = (char*)lds + both;          // B(t+1) dest
        char* As2 = (char*)lds + ann;           // A(t+2) dest

        // ---- p0: read a fm0-3 kk0 + b kk0; stage B0(t+1); BAR; MFMA; BAR ----
#pragma unroll
        for (int fm = 0; fm < 4; ++fm) ra[fm] = *(const bf16x8*)(Al + aBase + fm * 2048 + csw0);
#pragma unroll
        for (int fn = 0; fn < 4; ++fn) rb[fn] = *(const bf16x8*)(Bl + bBase + fn * 2048 + csw0);
        if (kt + 1 < NT) stageHalf(Bg(kt + 1, 0), Bs);
        asm volatile("s_barrier" ::: "memory");
        __builtin_amdgcn_s_setprio(1);
#pragma unroll
        for (int fm = 0; fm < 4; ++fm)
#pragma unroll
            for (int fn = 0; fn < 4; ++fn)
                acc[fm][fn] = __builtin_amdgcn_mfma_f32_16x16x32_bf16(ra[fm], rb[fn], acc[fm][fn], 0, 0, 0);
        __builtin_amdgcn_s_setprio(0);
        asm volatile("s_barrier" ::: "memory");

        // ---- p1: read a fm4-7 kk0; stage B1(t+1); BAR; MFMA; BAR ----
#pragma unroll
        for (int fm = 0; fm < 4; ++fm) ra[fm] = *(const bf16x8*)(Al + aBase + (fm + 4) * 2048 + csw0);
        if (kt + 1 < NT) stageHalf(Bg(kt + 1, 1), Bs + 16384);
        asm volatile("s_barrier" ::: "memory");
        __builtin_amdgcn_s_setprio(1);
#pragma unroll
        for (int fm = 0; fm < 4; ++fm)
#pragma unroll
            for (int fn = 0; fn < 4; ++fn)
                acc[fm + 4][fn] = __builtin_amdgcn_mfma_f32_16x16x32_bf16(ra[fm], rb[fn], acc[fm + 4][fn], 0, 0, 0);
        __builtin_amdgcn_s_setprio(0);
        asm volatile("s_barrier" ::: "memory");

        // ---- p2: read a fm0-3 kk1 + b kk1; stage A0(t+2); BAR; MFMA; BAR ----
#pragma unroll
        for (int fm = 0; fm < 4; ++fm) ra[fm] = *(const bf16x8*)(Al + aBase + fm * 2048 + csw1);
#pragma unroll
        for (int fn = 0; fn < 4; ++fn) rb[fn] = *(const bf16x8*)(Bl + bBase + fn * 2048 + csw1);
        if (kt + 2 < NT) stageHalf(Ag(kt + 2, 0), As2);
        asm volatile("s_barrier" ::: "memory");
        __builtin_amdgcn_s_setprio(1);
#pragma unroll
        for (int fm = 0; fm < 4; ++fm)
#pragma unroll
            for (int fn = 0; fn < 4; ++fn)
                acc[fm][fn] = __builtin_amdgcn_mfma_f32_16x16x32_bf16(ra[fm], rb[fn], acc[fm][fn], 0, 0, 0);
        __builtin_amdgcn_s_setprio(0);
        asm volatile("s_barrier" ::: "memory");

        // ---- p3: read a fm4-7 kk1; stage A1(t+2); BAR; MFMA; vmcnt(4); END ----
#pragma unroll
        for (int fm = 0; fm < 4; ++fm) ra[fm] = *(const bf16x8*)(Al + aBase + (fm + 4) * 2048 + csw1);
        if (kt + 2 < NT) stageHalf(Ag(kt + 2, 1), As2 + 16384);
        asm volatile("s_barrier" ::: "memory");
        __builtin_amdgcn_s_setprio(1);
#pragma unroll
        for (int fm = 0; fm < 4; ++fm)
#pragma unroll
            for (int fn = 0; fn < 4; ++fn)
                acc[fm + 4][fn] = __builtin_amdgcn_mfma_f32_16x16x32_bf16(ra[fm], rb[fn], acc[fm + 4][fn], 0, 0, 0);
        __builtin_amdgcn_s_setprio(0);
        if (kt + 1 < NT) {
            if (kt + 2 < NT) { asm volatile("s_waitcnt vmcnt(4)" ::: "memory"); }
            else             { asm volatile("s_waitcnt vmcnt(0)" ::: "memory"); }
            __builtin_amdgcn_sched_barrier(0);
        }
        asm volatile("s_barrier" ::: "memory");   // END: globalizes vmcnt + handoff

        const int at = acur; acur = anxt; anxt = ann; ann = at;
        const int bt = bcur; bcur = both; both = bt;
    }

    // epilogue: out = acc*scale + bias ; C/D layout col=lane&15, row=(lane>>4)*4+i
    const float scale = *wscale;
    const int orow0 = bm * 256 + wr * 128 + ((lane >> 4) << 2);
    const int ocol0 = bn * 256 + wc * 64  + (lane & 15);
#pragma unroll
    for (int fn = 0; fn < 4; ++fn) {
        const int col = ocol0 + 16 * fn;
        const float bb = bias[col];
#pragma unroll
        for (int fm = 0; fm < 8; ++fm) {
            const int row0 = orow0 + 16 * fm;
#pragma unroll
            for (int i = 0; i < 4; ++i)
                out[(size_t)(row0 + i) * N + col] = acc[fm][fn][i] * scale + bb;
        }
    }
}

// ---------- fallback: round-2 fused kernel (passes; used only if ws too small) ----------
__device__ __forceinline__ int swz(int row, int byte_in_row) {
    return row * 128 + (byte_in_row ^ ((row & 7) << 4));
}

__global__ __launch_bounds__(256) void qlinear_fused_kernel(
    const float* __restrict__ X, const int* __restrict__ W,
    const float* __restrict__ wscale, const float* __restrict__ bias,
    float* __restrict__ out, int M, int N, int K)
{
    __shared__ unsigned char smem[32768];

    const int t    = threadIdx.x;
    const int lane = t & 63;
    const int wid  = t >> 6;
    const int wr   = wid >> 1;
    const int wc   = wid & 1;

    const int ntn = N >> 7;
    const int bm  = blockIdx.x / ntn;
    const int bn  = blockIdx.x % ntn;
    const int NT  = K >> 6;

    const float* Ab = X + (size_t)bm * 128 * K;
    const int*   Bb = W + (size_t)bn * 128 * K;

    const int srow = t >> 4, sc4 = t & 15;

    f32x4 av[8];
    i32x4 bv[8];

    auto loadAB = [&](int kt) {
        const float* Ap = Ab + kt * 64 + sc4 * 4;
#pragma unroll
        for (int l = 0; l < 8; ++l)
            av[l] = *(const f32x4*)(Ap + (size_t)(srow + 16 * l) * K);
        const int* Bp = Bb + kt * 64 + sc4 * 4;
#pragma unroll
        for (int l = 0; l < 8; ++l)
            bv[l] = *(const i32x4*)(Bp + (size_t)(srow + 16 * l) * K);
    };

    auto writeAB = [&]() {
#pragma unroll
        for (int l = 0; l < 8; ++l) {
            const int row = srow + 16 * l;
            u32x2 pk;
            pk[0] = f2bf(av[l][0]) | (f2bf(av[l][1]) << 16);
            pk[1] = f2bf(av[l][2]) | (f2bf(av[l][3]) << 16);
            *(u32x2*)(smem + swz(row, sc4 * 8)) = pk;
        }
#pragma unroll
        for (int l = 0; l < 8; ++l) {
            const int row = srow + 16 * l;
            u32x2 pk;
            pk[0] = f2bf((float)bv[l][0]) | (f2bf((float)bv[l][1]) << 16);
            pk[1] = f2bf((float)bv[l][2]) | (f2bf((float)bv[l][3]) << 16);
            *(u32x2*)(smem + 16384 + swz(row, sc4 * 8)) = pk;
        }
    };

    f32x4 acc[4][4];
#pragma unroll
    for (int mi = 0; mi < 4; ++mi)
#pragma unroll
        for (int ni = 0; ni < 4; ++ni)
            acc[mi][ni] = (f32x4){0.f, 0.f, 0.f, 0.f};

    const int kbyte = (lane >> 4) * 16;
    const int afr   = wr * 64 + (lane & 15);
    const int bfr   = wc * 64 + (lane & 15);

    loadAB(0);

    for (int kt = 0; kt < NT; ++kt) {
        writeAB();
        __syncthreads();
        if (kt + 1 < NT) loadAB(kt + 1);
#pragma unroll
        for (int kk = 0; kk < 2; ++kk) {
            bf16x8 a[4], b[4];
#pragma unroll
            for (int mi = 0; mi < 4; ++mi)
                a[mi] = *(const bf16x8*)(smem + swz(afr + 16 * mi, kk * 64 + kbyte));
#pragma unroll
            for (int ni = 0; ni < 4; ++ni)
                b[ni] = *(const bf16x8*)(smem + 16384 + swz(bfr + 16 * ni, kk * 64 + kbyte));
#pragma unroll
            for (int mi = 0; mi < 4; ++mi)
#pragma unroll
                for (int ni = 0; ni < 4; ++ni)
                    acc[mi][ni] = __builtin_amdgcn_mfma_f32_16x16x32_bf16(
                        a[mi], b[ni], acc[mi][ni], 0, 0, 0);
        }
        __syncthreads();
    }

    const float scale = *wscale;
    const int orow0 = bm * 128 + wr * 64 + ((lane >> 4) << 2);
    const int ocol0 = bn * 128 + wc * 64 + (lane & 15);
#pragma unroll
    for (int ni = 0; ni < 4; ++ni) {
        const int col = ocol0 + 16 * ni;
        const float bb = bias[col];
#pragma unroll
        for (int mi = 0; mi < 4; ++mi) {
            const int row0 = orow0 + 16 * mi;
#pragma unroll
            for (int i = 0; i < 4; ++i)
                out[(size_t)(row0 + i) * N + col] = acc[mi][ni][i] * scale + bb;
        }
    }
}

extern "C" void kernel_launch(void* const* d_in, const int* in_sizes, int n_in,
                              void* d_out, int out_size, void* d_ws, size_t ws_size,
                              hipStream_t stream) {
    const float* x      = (const float*)d_in[0];
    const int*   w      = (const int*)d_in[1];      // int inputs arrive as int32
    const float* wscale = (const float*)d_in[2];
    const float* bias   = (const float*)d_in[3];
    float*       out    = (float*)d_out;

    const int DOUT = in_sizes[3];
    const int DIN  = in_sizes[1] / DOUT;
    const int M    = in_sizes[0] / DIN;

    const size_t xb_bytes = (size_t)M * DIN * 2;
    const size_t wb_bytes = (size_t)DOUT * DIN * 2;

    if (ws_size >= xb_bytes + wb_bytes && (M % 256) == 0 && (DOUT % 256) == 0
        && (DIN % 64) == 0 && (DIN / 64) >= 2) {
        unsigned short* xb = (unsigned short*)d_ws;
        unsigned short* wb = (unsigned short*)((char*)d_ws + xb_bytes);

        const long long nx8 = (long long)M * DIN / 8;
        const long long nw8 = (long long)DOUT * DIN / 8;
        convert_x_kernel<<<2048, 256, 0, stream>>>(x, xb, nx8);
        convert_w_kernel<<<2048, 256, 0, stream>>>(w, wb, nw8);

        dim3 grid((M / 256) * (DOUT / 256));
        gemm256_kernel<<<grid, 512, 0, stream>>>(xb, wb, wscale, bias, out, M, DOUT, DIN);
    } else {
        dim3 grid((M / 128) * (DOUT / 128));
        qlinear_fused_kernel<<<grid, 256, 0, stream>>>(x, w, wscale, bias, out, M, DOUT, DIN);
    }
}

// Round 13
// 289.799 us; speedup vs baseline: 1.1345x; 1.0288x over previous
//
#include <hip/hip_runtime.h>
#include <hip/hip_bf16.h>

typedef __attribute__((ext_vector_type(8))) short bf16x8;
typedef __attribute__((ext_vector_type(4))) float f32x4;
typedef __attribute__((ext_vector_type(4))) int i32x4;
typedef __attribute__((ext_vector_type(2))) unsigned int u32x2;
typedef __attribute__((ext_vector_type(4))) unsigned int u32x4;

// RNE fp32 -> bf16 bits (inputs finite; no NaN handling needed)
__device__ __forceinline__ unsigned int f2bf(float f) {
    union { float f; unsigned int u; } v; v.f = f;
    unsigned int u = v.u;
    u += 0x7FFFu + ((u >> 16) & 1u);
    return u >> 16;
}

__device__ __forceinline__ void gl_lds16(const void* gptr, void* lptr) {
    __builtin_amdgcn_global_load_lds(
        (const __attribute__((address_space(1))) unsigned int*)gptr,
        (__attribute__((address_space(3))) unsigned int*)lptr, 16, 0, 0);
}

// ---------- fused pre-pass convert: x (fp32->bf16) and W (int32->bf16) ----------
__global__ __launch_bounds__(256) void convert_xw_kernel(
    const float* __restrict__ x, const int* __restrict__ w,
    unsigned short* __restrict__ xb, unsigned short* __restrict__ wb,
    long long nx8, long long ntot8)
{
    long long i = (long long)blockIdx.x * blockDim.x + threadIdx.x;
    const long long stride = (long long)gridDim.x * blockDim.x;
    for (; i < ntot8; i += stride) {
        if (i < nx8) {
            const f32x4* p = (const f32x4*)(x + i * 8);
            f32x4 v0 = p[0], v1 = p[1];
            u32x4 q;
            q[0] = f2bf(v0[0]) | (f2bf(v0[1]) << 16);
            q[1] = f2bf(v0[2]) | (f2bf(v0[3]) << 16);
            q[2] = f2bf(v1[0]) | (f2bf(v1[1]) << 16);
            q[3] = f2bf(v1[2]) | (f2bf(v1[3]) << 16);
            *(u32x4*)(xb + i * 8) = q;
        } else {
            const long long j = i - nx8;
            const i32x4* p = (const i32x4*)(w + j * 8);
            i32x4 v0 = p[0], v1 = p[1];
            u32x4 q;   // int8 values are exact in bf16
            q[0] = f2bf((float)v0[0]) | (f2bf((float)v0[1]) << 16);
            q[1] = f2bf((float)v0[2]) | (f2bf((float)v0[3]) << 16);
            q[2] = f2bf((float)v1[0]) | (f2bf((float)v1[1]) << 16);
            q[3] = f2bf((float)v1[2]) | (f2bf((float)v1[3]) << 16);
            *(u32x4*)(wb + j * 8) = q;
        }
    }
}

// ---------- 256x256 pipelined GEMM, A tribuf / B dbuf (r9-verified schedule) ----------
// 512 thr = 8 waves in 4Mx2N; per-wave out 64x128. BK=64.
// LDS 160KB: A tribuf 3x32KB @ {0,32768,65536}; B dbuf 2x32KB @ {98304,131072}.
// Phase p issues phase p+1's ds_reads; MFMAs run on regs read last phase.
// Stage rotation during tile t: p0/p1 -> B(t+1) halves; p2/p3 -> A(t+2) halves
// (into A(t-1)'s buffer, freed via END(t-1)). 2 barriers/tile:
//   B3  (p3, after vmcnt(4)): globalizes per-wave vmcnt -> tile t+1 fully
//       DMA-complete across ALL waves before any prefetch-read of it.
//   END (end p3): all tile-t reads operand-waited -> next tile may DMA.
// NEW vs r9: 8x8-supertile XCD mapping (each XCD works an 8bm x 8bn square ->
// 16 unique 32KB tile-slices/K-step/XCD, A+B each reused 8x in L2, vs 20
// slices and 4x B-reuse for the chunked-stripe swizzle).
__global__ __launch_bounds__(512, 2) void gemm256_kernel(
    const unsigned short* __restrict__ A, const unsigned short* __restrict__ Bw,
    const float* __restrict__ wscale, const float* __restrict__ bias,
    float* __restrict__ out, int M, int N, int K)
{
    __shared__ unsigned char lds[163840];
    const int B0OFF = 98304;

    const int tid  = threadIdx.x;
    const int lane = tid & 63;
    const int wid  = tid >> 6;
    const int wr   = wid >> 1;   // 0..3 -> 64 output rows each
    const int wc   = wid & 1;    // 0..1 -> 128 output cols each

    const int ntn = N >> 8;
    const int ntm = M >> 8;
    const int nwg = gridDim.x;
    int bm, bn;
    if ((ntm & 7) == 0 && (ntn & 7) == 0 && (ntm >> 3) * (ntn >> 3) == 8) {
        // 8x8 supertile per XCD: xcd = bid&7, time = bid>>3
        const int xcd = blockIdx.x & 7;
        const int t   = blockIdx.x >> 3;
        const int spy = ntn >> 3;                  // supertiles along n
        bm = (xcd / spy) * 8 + (t >> 3);
        bn = (xcd % spy) * 8 + (t & 7);
    } else {
        int bid = blockIdx.x;
        if ((nwg & 7) == 0) {                      // fallback: chunked XCD swizzle
            const int cpx = nwg >> 3;
            bid = (bid & 7) * cpx + (bid >> 3);
        }
        bm = bid / ntn;
        bn = bid % ntn;
    }
    const int NT = K >> 6;

    const char* Abase = (const char*)(A  + (size_t)bm * 256 * K);
    const char* Bbase = (const char*)(Bw + (size_t)bn * 256 * K);
    const size_t rowb = (size_t)K * 2;

    // staging: half-tile = 128 rows x 128B (16KB); 2 gl_lds per thread.
    // Linear LDS dest; source column pre-swizzled (rule 21).
    const int s_colb = (((lane & 7) ^ (lane >> 3)) << 4);
    const int s_rsub = wid * 8 + (lane >> 3);
    const int s_ldso = wid * 1024 + lane * 16;

    auto stageHalf = [&](const char* gRowBase, char* lhalf) {
#pragma unroll
        for (int q = 0; q < 2; ++q)
            gl_lds16(gRowBase + (size_t)(q * 64 + s_rsub) * rowb + s_colb,
                     lhalf + q * 8192 + s_ldso);
    };
    auto Ag = [&](int kt, int h) { return Abase + (size_t)kt * 128 + (size_t)(h * 128) * rowb; };
    auto Bg = [&](int kt, int h) { return Bbase + (size_t)kt * 128 + (size_t)(h * 128) * rowb; };

    // fragment-read addressing (swizzled)
    const int arow = (wr * 64  + (lane & 15)) * 128;
    const int brow = (wc * 128 + (lane & 15)) * 128;
    const int csw0 = (((lane >> 4) * 16))      ^ ((lane & 7) << 4);
    const int csw1 = (((lane >> 4) * 16) + 64) ^ ((lane & 7) << 4);

    f32x4 acc[4][8];
#pragma unroll
    for (int mi = 0; mi < 4; ++mi)
#pragma unroll
        for (int ni = 0; ni < 8; ++ni)
            acc[mi][ni] = (f32x4){0.f, 0.f, 0.f, 0.f};

    bf16x8 a0[4], a1[4], bA[4], bB[4];

    // ---- prologue: A(0)->Abuf0, B(0)->Bbuf0, A(1)->Abuf1; tile0 must land ----
    stageHalf(Ag(0, 0), (char*)lds + 0);
    stageHalf(Ag(0, 1), (char*)lds + 16384);
    stageHalf(Bg(0, 0), (char*)lds + B0OFF);
    stageHalf(Bg(0, 1), (char*)lds + B0OFF + 16384);
    if (NT > 1) {
        stageHalf(Ag(1, 0), (char*)lds + 32768);
        stageHalf(Ag(1, 1), (char*)lds + 32768 + 16384);
        asm volatile("s_waitcnt vmcnt(4)" ::: "memory");   // A(1) may stay in flight
    } else {
        asm volatile("s_waitcnt vmcnt(0)" ::: "memory");
    }
    __builtin_amdgcn_sched_barrier(0);
    asm volatile("s_barrier" ::: "memory");
    // R0 of tile 0: a0 (kk0) + bA (fn0-3, kk0)
    {
        const char* Al = (const char*)lds;
        const char* Bl = (const char*)lds + B0OFF;
#pragma unroll
        for (int fm = 0; fm < 4; ++fm) a0[fm] = *(const bf16x8*)(Al + arow + fm * 2048 + csw0);
#pragma unroll
        for (int fn = 0; fn < 4; ++fn) bA[fn] = *(const bf16x8*)(Bl + brow + fn * 2048 + csw0);
    }

    int acur = 0, anxt = 32768, ann = 65536;   // A tribuf rotation
    int bcur = B0OFF, both = B0OFF + 32768;    // B dbuf

    for (int kt = 0; kt < NT; ++kt) {
        const char* Al = (const char*)lds + acur;
        const char* Bl = (const char*)lds + bcur;
        char* Bs  = (char*)lds + both;          // B(t+1) dest (other B buf)
        char* As2 = (char*)lds + ann;           // A(t+2) dest (A(t-1)'s buf)

        // ---- p0: stage B0(t+1); read R1 {a1 kk1, bB fn4-7 kk0}; MFMA a0 x bA ----
        if (kt + 1 < NT) stageHalf(Bg(kt + 1, 0), Bs);
#pragma unroll
        for (int fm = 0; fm < 4; ++fm) a1[fm] = *(const bf16x8*)(Al + arow + fm * 2048 + csw1);
#pragma unroll
        for (int fn = 0; fn < 4; ++fn) bB[fn] = *(const bf16x8*)(Bl + brow + (fn + 4) * 2048 + csw0);
        __builtin_amdgcn_s_setprio(1);
#pragma unroll
        for (int fm = 0; fm < 4; ++fm)
#pragma unroll
            for (int fn = 0; fn < 4; ++fn)
                acc[fm][fn] = __builtin_amdgcn_mfma_f32_16x16x32_bf16(a0[fm], bA[fn], acc[fm][fn], 0, 0, 0);
        __builtin_amdgcn_s_setprio(0);

        // ---- p1: stage B1(t+1); read R2 {bA <- fn0-3 kk1}; MFMA a0 x bB ----
        if (kt + 1 < NT) stageHalf(Bg(kt + 1, 1), Bs + 16384);
#pragma unroll
        for (int fn = 0; fn < 4; ++fn) bA[fn] = *(const bf16x8*)(Bl + brow + fn * 2048 + csw1);
        __builtin_amdgcn_s_setprio(1);
#pragma unroll
        for (int fm = 0; fm < 4; ++fm)
#pragma unroll
            for (int fn = 0; fn < 4; ++fn)
                acc[fm][fn + 4] = __builtin_amdgcn_mfma_f32_16x16x32_bf16(a0[fm], bB[fn], acc[fm][fn + 4], 0, 0, 0);
        __builtin_amdgcn_s_setprio(0);
        // (no MID barrier: A(t+2) goes to A(t-1)'s buffer, freed via END(t-1))

        // ---- p2: stage A0(t+2); read R3 {bB <- fn4-7 kk1}; MFMA a1 x bA ----
        if (kt + 2 < NT) stageHalf(Ag(kt + 2, 0), As2);
#pragma unroll
        for (int fn = 0; fn < 4; ++fn) bB[fn] = *(const bf16x8*)(Bl + brow + (fn + 4) * 2048 + csw1);
        __builtin_amdgcn_s_setprio(1);
#pragma unroll
        for (int fm = 0; fm < 4; ++fm)
#pragma unroll
            for (int fn = 0; fn < 4; ++fn)
                acc[fm][fn] = __builtin_amdgcn_mfma_f32_16x16x32_bf16(a1[fm], bA[fn], acc[fm][fn], 0, 0, 0);
        __builtin_amdgcn_s_setprio(0);

        // ---- p3: stage A1(t+2); vmcnt(4); B3; read R0'(t+1); MFMA a1 x bB; END ----
        if (kt + 2 < NT) stageHalf(Ag(kt + 2, 1), As2 + 16384);
        if (kt + 1 < NT) {
            if (kt + 2 < NT) { asm volatile("s_waitcnt vmcnt(4)" ::: "memory"); }
            else             { asm volatile("s_waitcnt vmcnt(0)" ::: "memory"); }
            __builtin_amdgcn_sched_barrier(0);
            asm volatile("s_barrier" ::: "memory");          // B3: globalize vmcnt ->
                                                             // tile t+1 fully landed
            const char* nAl = (const char*)lds + anxt;
            const char* nBl = (const char*)lds + both;
#pragma unroll
            for (int fm = 0; fm < 4; ++fm) a0[fm] = *(const bf16x8*)(nAl + arow + fm * 2048 + csw0);
#pragma unroll
            for (int fn = 0; fn < 4; ++fn) bA[fn] = *(const bf16x8*)(nBl + brow + fn * 2048 + csw0);
        }
        __builtin_amdgcn_s_setprio(1);
#pragma unroll
        for (int fm = 0; fm < 4; ++fm)
#pragma unroll
            for (int fn = 0; fn < 4; ++fn)
                acc[fm][fn + 4] = __builtin_amdgcn_mfma_f32_16x16x32_bf16(a1[fm], bB[fn], acc[fm][fn + 4], 0, 0, 0);
        __builtin_amdgcn_s_setprio(0);
        asm volatile("s_barrier" ::: "memory");              // END: region handoff + swap

        const int at = acur; acur = anxt; anxt = ann; ann = at;
        const int bt = bcur; bcur = both; both = bt;
    }

    // epilogue: out = acc*scale + bias ; C/D layout col=lane&15, row=(lane>>4)*4+i
    const float scale = *wscale;
    const int orow0 = bm * 256 + wr * 64  + ((lane >> 4) << 2);
    const int ocol0 = bn * 256 + wc * 128 + (lane & 15);
#pragma unroll
    for (int fn = 0; fn < 8; ++fn) {
        const int col = ocol0 + 16 * fn;
        const float bb = bias[col];
#pragma unroll
        for (int fm = 0; fm < 4; ++fm) {
            const int row0 = orow0 + 16 * fm;
#pragma unroll
            for (int i = 0; i < 4; ++i)
                out[(size_t)(row0 + i) * N + col] = acc[fm][fn][i] * scale + bb;
        }
    }
}

// ---------- fallback: round-2 fused kernel (passes; used only if ws too small) ----------
__device__ __forceinline__ int swz(int row, int byte_in_row) {
    return row * 128 + (byte_in_row ^ ((row & 7) << 4));
}

__global__ __launch_bounds__(256) void qlinear_fused_kernel(
    const float* __restrict__ X, const int* __restrict__ W,
    const float* __restrict__ wscale, const float* __restrict__ bias,
    float* __restrict__ out, int M, int N, int K)
{
    __shared__ unsigned char smem[32768];

    const int t    = threadIdx.x;
    const int lane = t & 63;
    const int wid  = t >> 6;
    const int wr   = wid >> 1;
    const int wc   = wid & 1;

    const int ntn = N >> 7;
    const int bm  = blockIdx.x / ntn;
    const int bn  = blockIdx.x % ntn;
    const int NT  = K >> 6;

    const float* Ab = X + (size_t)bm * 128 * K;
    const int*   Bb = W + (size_t)bn * 128 * K;

    const int srow = t >> 4, sc4 = t & 15;

    f32x4 av[8];
    i32x4 bv[8];

    auto loadAB = [&](int kt) {
        const float* Ap = Ab + kt * 64 + sc4 * 4;
#pragma unroll
        for (int l = 0; l < 8; ++l)
            av[l] = *(const f32x4*)(Ap + (size_t)(srow + 16 * l) * K);
        const int* Bp = Bb + kt * 64 + sc4 * 4;
#pragma unroll
        for (int l = 0; l < 8; ++l)
            bv[l] = *(const i32x4*)(Bp + (size_t)(srow + 16 * l) * K);
    };

    auto writeAB = [&]() {
#pragma unroll
        for (int l = 0; l < 8; ++l) {
            const int row = srow + 16 * l;
            u32x2 pk;
            pk[0] = f2bf(av[l][0]) | (f2bf(av[l][1]) << 16);
            pk[1] = f2bf(av[l][2]) | (f2bf(av[l][3]) << 16);
            *(u32x2*)(smem + swz(row, sc4 * 8)) = pk;
        }
#pragma unroll
        for (int l = 0; l < 8; ++l) {
            const int row = srow + 16 * l;
            u32x2 pk;
            pk[0] = f2bf((float)bv[l][0]) | (f2bf((float)bv[l][1]) << 16);
            pk[1] = f2bf((float)bv[l][2]) | (f2bf((float)bv[l][3]) << 16);
            *(u32x2*)(smem + 16384 + swz(row, sc4 * 8)) = pk;
        }
    };

    f32x4 acc[4][4];
#pragma unroll
    for (int mi = 0; mi < 4; ++mi)
#pragma unroll
        for (int ni = 0; ni < 4; ++ni)
            acc[mi][ni] = (f32x4){0.f, 0.f, 0.f, 0.f};

    const int kbyte = (lane >> 4) * 16;
    const int afr   = wr * 64 + (lane & 15);
    const int bfr   = wc * 64 + (lane & 15);

    loadAB(0);

    for (int kt = 0; kt < NT; ++kt) {
        writeAB();
        __syncthreads();
        if (kt + 1 < NT) loadAB(kt + 1);
#pragma unroll
        for (int kk = 0; kk < 2; ++kk) {
            bf16x8 a[4], b[4];
#pragma unroll
            for (int mi = 0; mi < 4; ++mi)
                a[mi] = *(const bf16x8*)(smem + swz(afr + 16 * mi, kk * 64 + kbyte));
#pragma unroll
            for (int ni = 0; ni < 4; ++ni)
                b[ni] = *(const bf16x8*)(smem + 16384 + swz(bfr + 16 * ni, kk * 64 + kbyte));
#pragma unroll
            for (int mi = 0; mi < 4; ++mi)
#pragma unroll
                for (int ni = 0; ni < 4; ++ni)
                    acc[mi][ni] = __builtin_amdgcn_mfma_f32_16x16x32_bf16(
                        a[mi], b[ni], acc[mi][ni], 0, 0, 0);
        }
        __syncthreads();
    }

    const float scale = *wscale;
    const int orow0 = bm * 128 + wr * 64 + ((lane >> 4) << 2);
    const int ocol0 = bn * 128 + wc * 64 + (lane & 15);
#pragma unroll
    for (int ni = 0; ni < 4; ++ni) {
        const int col = ocol0 + 16 * ni;
        const float bb = bias[col];
#pragma unroll
        for (int mi = 0; mi < 4; ++mi) {
            const int row0 = orow0 + 16 * mi;
#pragma unroll
            for (int i = 0; i < 4; ++i)
                out[(size_t)(row0 + i) * N + col] = acc[mi][ni][i] * scale + bb;
        }
    }
}

extern "C" void kernel_launch(void* const* d_in, const int* in_sizes, int n_in,
                              void* d_out, int out_size, void* d_ws, size_t ws_size,
                              hipStream_t stream) {
    const float* x      = (const float*)d_in[0];
    const int*   w      = (const int*)d_in[1];      // int inputs arrive as int32
    const float* wscale = (const float*)d_in[2];
    const float* bias   = (const float*)d_in[3];
    float*       out    = (float*)d_out;

    const int DOUT = in_sizes[3];
    const int DIN  = in_sizes[1] / DOUT;
    const int M    = in_sizes[0] / DIN;

    const size_t xb_bytes = (size_t)M * DIN * 2;
    const size_t wb_bytes = (size_t)DOUT * DIN * 2;

    if (ws_size >= xb_bytes + wb_bytes && (M % 256) == 0 && (DOUT % 256) == 0
        && (DIN % 64) == 0 && (DIN / 64) >= 2) {
        unsigned short* xb = (unsigned short*)d_ws;
        unsigned short* wb = (unsigned short*)((char*)d_ws + xb_bytes);

        const long long nx8 = (long long)M * DIN / 8;
        const long long nw8 = (long long)DOUT * DIN / 8;
        convert_xw_kernel<<<2048, 256, 0, stream>>>(x, w, xb, wb, nx8, nx8 + nw8);

        dim3 grid((M / 256) * (DOUT / 256));
        gemm256_kernel<<<grid, 512, 0, stream>>>(xb, wb, wscale, bias, out, M, DOUT, DIN);
    } else {
        dim3 grid((M / 128) * (DOUT / 128));
        qlinear_fused_kernel<<<grid, 256, 0, stream>>>(x, w, wscale, bias, out, M, DOUT, DIN);
    }
}

// Round 14
// 278.335 us; speedup vs baseline: 1.1812x; 1.0412x over previous
//
#include <hip/hip_runtime.h>
#include <hip/hip_bf16.h>

typedef __attribute__((ext_vector_type(8))) short bf16x8;
typedef __attribute__((ext_vector_type(4))) float f32x4;
typedef __attribute__((ext_vector_type(4))) int i32x4;
typedef __attribute__((ext_vector_type(2))) unsigned int u32x2;
typedef __attribute__((ext_vector_type(4))) unsigned int u32x4;

// RNE fp32 -> bf16 bits (inputs finite; no NaN handling needed)
__device__ __forceinline__ unsigned int f2bf(float f) {
    union { float f; unsigned int u; } v; v.f = f;
    unsigned int u = v.u;
    u += 0x7FFFu + ((u >> 16) & 1u);
    return u >> 16;
}

__device__ __forceinline__ void gl_lds16(const void* gptr, void* lptr) {
    __builtin_amdgcn_global_load_lds(
        (const __attribute__((address_space(1))) unsigned int*)gptr,
        (__attribute__((address_space(3))) unsigned int*)lptr, 16, 0, 0);
}

// ---------- fused pre-pass convert: x (fp32->bf16) and W (int32->bf16) ----------
__global__ __launch_bounds__(256) void convert_xw_kernel(
    const float* __restrict__ x, const int* __restrict__ w,
    unsigned short* __restrict__ xb, unsigned short* __restrict__ wb,
    long long nx8, long long ntot8)
{
    long long i = (long long)blockIdx.x * blockDim.x + threadIdx.x;
    const long long stride = (long long)gridDim.x * blockDim.x;
    for (; i < ntot8; i += stride) {
        if (i < nx8) {
            const f32x4* p = (const f32x4*)(x + i * 8);
            f32x4 v0 = p[0], v1 = p[1];
            u32x4 q;
            q[0] = f2bf(v0[0]) | (f2bf(v0[1]) << 16);
            q[1] = f2bf(v0[2]) | (f2bf(v0[3]) << 16);
            q[2] = f2bf(v1[0]) | (f2bf(v1[1]) << 16);
            q[3] = f2bf(v1[2]) | (f2bf(v1[3]) << 16);
            *(u32x4*)(xb + i * 8) = q;
        } else {
            const long long j = i - nx8;
            const i32x4* p = (const i32x4*)(w + j * 8);
            i32x4 v0 = p[0], v1 = p[1];
            u32x4 q;   // int8 values are exact in bf16
            q[0] = f2bf((float)v0[0]) | (f2bf((float)v0[1]) << 16);
            q[1] = f2bf((float)v0[2]) | (f2bf((float)v0[3]) << 16);
            q[2] = f2bf((float)v1[0]) | (f2bf((float)v1[1]) << 16);
            q[3] = f2bf((float)v1[2]) | (f2bf((float)v1[3]) << 16);
            *(u32x4*)(wb + j * 8) = q;
        }
    }
}

// ---------- 256x256 pipelined GEMM, A tribuf / B dbuf (r9-verified schedule) ----------
// Best measured configuration of this session: 242 us GEMM, MfmaUtil 50.8%,
// 0 bank conflicts. 512 thr = 8 waves in 4Mx2N; per-wave out 64x128. BK=64.
// LDS 160KB: A tribuf 3x32KB @ {0,32768,65536}; B dbuf 2x32KB @ {98304,131072}.
// Phase p issues phase p+1's ds_reads; MFMAs run on regs read last phase.
// Stage rotation during tile t: p0/p1 -> B(t+1) halves; p2/p3 -> A(t+2) halves
// (into A(t-1)'s buffer, freed via END(t-1)). 2 barriers/tile:
//   B3  (p3, after vmcnt(4)): globalizes per-wave vmcnt -> tile t+1 fully
//       DMA-complete across ALL waves before any prefetch-read of it (r6 race).
//   END (end p3): all tile-t reads operand-waited -> next tile may DMA.
// Session ledger: supertile L2 map cut FETCH 35% but slowed dur (r13);
// B-tribuf depth null (r8); per-phase interleave, 32x32 MFMA, 2-block TLP
// all regressed (r10-r12). This structure is the measured local optimum.
__global__ __launch_bounds__(512, 2) void gemm256_kernel(
    const unsigned short* __restrict__ A, const unsigned short* __restrict__ Bw,
    const float* __restrict__ wscale, const float* __restrict__ bias,
    float* __restrict__ out, int M, int N, int K)
{
    __shared__ unsigned char lds[163840];
    const int B0OFF = 98304;

    const int tid  = threadIdx.x;
    const int lane = tid & 63;
    const int wid  = tid >> 6;
    const int wr   = wid >> 1;   // 0..3 -> 64 output rows each
    const int wc   = wid & 1;    // 0..1 -> 128 output cols each

    const int ntn = N >> 8;
    const int nwg = gridDim.x;
    int bid = blockIdx.x;
    if ((nwg & 7) == 0) {                       // XCD-aware chunked swizzle (T1)
        const int cpx = nwg >> 3;
        bid = (bid & 7) * cpx + (bid >> 3);
    }
    const int bm = bid / ntn;
    const int bn = bid % ntn;
    const int NT = K >> 6;

    const char* Abase = (const char*)(A  + (size_t)bm * 256 * K);
    const char* Bbase = (const char*)(Bw + (size_t)bn * 256 * K);
    const size_t rowb = (size_t)K * 2;

    // staging: half-tile = 128 rows x 128B (16KB); 2 gl_lds per thread.
    // Linear LDS dest; source column pre-swizzled (rule 21).
    const int s_colb = (((lane & 7) ^ (lane >> 3)) << 4);
    const int s_rsub = wid * 8 + (lane >> 3);
    const int s_ldso = wid * 1024 + lane * 16;

    auto stageHalf = [&](const char* gRowBase, char* lhalf) {
#pragma unroll
        for (int q = 0; q < 2; ++q)
            gl_lds16(gRowBase + (size_t)(q * 64 + s_rsub) * rowb + s_colb,
                     lhalf + q * 8192 + s_ldso);
    };
    auto Ag = [&](int kt, int h) { return Abase + (size_t)kt * 128 + (size_t)(h * 128) * rowb; };
    auto Bg = [&](int kt, int h) { return Bbase + (size_t)kt * 128 + (size_t)(h * 128) * rowb; };

    // fragment-read addressing (swizzled)
    const int arow = (wr * 64  + (lane & 15)) * 128;
    const int brow = (wc * 128 + (lane & 15)) * 128;
    const int csw0 = (((lane >> 4) * 16))      ^ ((lane & 7) << 4);
    const int csw1 = (((lane >> 4) * 16) + 64) ^ ((lane & 7) << 4);

    f32x4 acc[4][8];
#pragma unroll
    for (int mi = 0; mi < 4; ++mi)
#pragma unroll
        for (int ni = 0; ni < 8; ++ni)
            acc[mi][ni] = (f32x4){0.f, 0.f, 0.f, 0.f};

    bf16x8 a0[4], a1[4], bA[4], bB[4];

    // ---- prologue: A(0)->Abuf0, B(0)->Bbuf0, A(1)->Abuf1; tile0 must land ----
    stageHalf(Ag(0, 0), (char*)lds + 0);
    stageHalf(Ag(0, 1), (char*)lds + 16384);
    stageHalf(Bg(0, 0), (char*)lds + B0OFF);
    stageHalf(Bg(0, 1), (char*)lds + B0OFF + 16384);
    if (NT > 1) {
        stageHalf(Ag(1, 0), (char*)lds + 32768);
        stageHalf(Ag(1, 1), (char*)lds + 32768 + 16384);
        asm volatile("s_waitcnt vmcnt(4)" ::: "memory");   // A(1) may stay in flight
    } else {
        asm volatile("s_waitcnt vmcnt(0)" ::: "memory");
    }
    __builtin_amdgcn_sched_barrier(0);
    asm volatile("s_barrier" ::: "memory");
    // R0 of tile 0: a0 (kk0) + bA (fn0-3, kk0)
    {
        const char* Al = (const char*)lds;
        const char* Bl = (const char*)lds + B0OFF;
#pragma unroll
        for (int fm = 0; fm < 4; ++fm) a0[fm] = *(const bf16x8*)(Al + arow + fm * 2048 + csw0);
#pragma unroll
        for (int fn = 0; fn < 4; ++fn) bA[fn] = *(const bf16x8*)(Bl + brow + fn * 2048 + csw0);
    }

    int acur = 0, anxt = 32768, ann = 65536;   // A tribuf rotation
    int bcur = B0OFF, both = B0OFF + 32768;    // B dbuf

    for (int kt = 0; kt < NT; ++kt) {
        const char* Al = (const char*)lds + acur;
        const char* Bl = (const char*)lds + bcur;
        char* Bs  = (char*)lds + both;          // B(t+1) dest (other B buf)
        char* As2 = (char*)lds + ann;           // A(t+2) dest (A(t-1)'s buf)

        // ---- p0: stage B0(t+1); read R1 {a1 kk1, bB fn4-7 kk0}; MFMA a0 x bA ----
        if (kt + 1 < NT) stageHalf(Bg(kt + 1, 0), Bs);
#pragma unroll
        for (int fm = 0; fm < 4; ++fm) a1[fm] = *(const bf16x8*)(Al + arow + fm * 2048 + csw1);
#pragma unroll
        for (int fn = 0; fn < 4; ++fn) bB[fn] = *(const bf16x8*)(Bl + brow + (fn + 4) * 2048 + csw0);
        __builtin_amdgcn_s_setprio(1);
#pragma unroll
        for (int fm = 0; fm < 4; ++fm)
#pragma unroll
            for (int fn = 0; fn < 4; ++fn)
                acc[fm][fn] = __builtin_amdgcn_mfma_f32_16x16x32_bf16(a0[fm], bA[fn], acc[fm][fn], 0, 0, 0);
        __builtin_amdgcn_s_setprio(0);

        // ---- p1: stage B1(t+1); read R2 {bA <- fn0-3 kk1}; MFMA a0 x bB ----
        if (kt + 1 < NT) stageHalf(Bg(kt + 1, 1), Bs + 16384);
#pragma unroll
        for (int fn = 0; fn < 4; ++fn) bA[fn] = *(const bf16x8*)(Bl + brow + fn * 2048 + csw1);
        __builtin_amdgcn_s_setprio(1);
#pragma unroll
        for (int fm = 0; fm < 4; ++fm)
#pragma unroll
            for (int fn = 0; fn < 4; ++fn)
                acc[fm][fn + 4] = __builtin_amdgcn_mfma_f32_16x16x32_bf16(a0[fm], bB[fn], acc[fm][fn + 4], 0, 0, 0);
        __builtin_amdgcn_s_setprio(0);
        // (no MID barrier: A(t+2) goes to A(t-1)'s buffer, freed via END(t-1))

        // ---- p2: stage A0(t+2); read R3 {bB <- fn4-7 kk1}; MFMA a1 x bA ----
        if (kt + 2 < NT) stageHalf(Ag(kt + 2, 0), As2);
#pragma unroll
        for (int fn = 0; fn < 4; ++fn) bB[fn] = *(const bf16x8*)(Bl + brow + (fn + 4) * 2048 + csw1);
        __builtin_amdgcn_s_setprio(1);
#pragma unroll
        for (int fm = 0; fm < 4; ++fm)
#pragma unroll
            for (int fn = 0; fn < 4; ++fn)
                acc[fm][fn] = __builtin_amdgcn_mfma_f32_16x16x32_bf16(a1[fm], bA[fn], acc[fm][fn], 0, 0, 0);
        __builtin_amdgcn_s_setprio(0);

        // ---- p3: stage A1(t+2); vmcnt(4); B3; read R0'(t+1); MFMA a1 x bB; END ----
        if (kt + 2 < NT) stageHalf(Ag(kt + 2, 1), As2 + 16384);
        if (kt + 1 < NT) {
            if (kt + 2 < NT) { asm volatile("s_waitcnt vmcnt(4)" ::: "memory"); }
            else             { asm volatile("s_waitcnt vmcnt(0)" ::: "memory"); }
            __builtin_amdgcn_sched_barrier(0);
            asm volatile("s_barrier" ::: "memory");          // B3: globalize vmcnt ->
                                                             // tile t+1 fully landed
            const char* nAl = (const char*)lds + anxt;
            const char* nBl = (const char*)lds + both;
#pragma unroll
            for (int fm = 0; fm < 4; ++fm) a0[fm] = *(const bf16x8*)(nAl + arow + fm * 2048 + csw0);
#pragma unroll
            for (int fn = 0; fn < 4; ++fn) bA[fn] = *(const bf16x8*)(nBl + brow + fn * 2048 + csw0);
        }
        __builtin_amdgcn_s_setprio(1);
#pragma unroll
        for (int fm = 0; fm < 4; ++fm)
#pragma unroll
            for (int fn = 0; fn < 4; ++fn)
                acc[fm][fn + 4] = __builtin_amdgcn_mfma_f32_16x16x32_bf16(a1[fm], bB[fn], acc[fm][fn + 4], 0, 0, 0);
        __builtin_amdgcn_s_setprio(0);
        asm volatile("s_barrier" ::: "memory");              // END: region handoff + swap

        const int at = acur; acur = anxt; anxt = ann; ann = at;
        const int bt = bcur; bcur = both; both = bt;
    }

    // epilogue: out = acc*scale + bias ; C/D layout col=lane&15, row=(lane>>4)*4+i
    const float scale = *wscale;
    const int orow0 = bm * 256 + wr * 64  + ((lane >> 4) << 2);
    const int ocol0 = bn * 256 + wc * 128 + (lane & 15);
#pragma unroll
    for (int fn = 0; fn < 8; ++fn) {
        const int col = ocol0 + 16 * fn;
        const float bb = bias[col];
#pragma unroll
        for (int fm = 0; fm < 4; ++fm) {
            const int row0 = orow0 + 16 * fm;
#pragma unroll
            for (int i = 0; i < 4; ++i)
                out[(size_t)(row0 + i) * N + col] = acc[fm][fn][i] * scale + bb;
        }
    }
}

// ---------- fallback: round-2 fused kernel (passes; used only if ws too small) ----------
__device__ __forceinline__ int swz(int row, int byte_in_row) {
    return row * 128 + (byte_in_row ^ ((row & 7) << 4));
}

__global__ __launch_bounds__(256) void qlinear_fused_kernel(
    const float* __restrict__ X, const int* __restrict__ W,
    const float* __restrict__ wscale, const float* __restrict__ bias,
    float* __restrict__ out, int M, int N, int K)
{
    __shared__ unsigned char smem[32768];

    const int t    = threadIdx.x;
    const int lane = t & 63;
    const int wid  = t >> 6;
    const int wr   = wid >> 1;
    const int wc   = wid & 1;

    const int ntn = N >> 7;
    const int bm  = blockIdx.x / ntn;
    const int bn  = blockIdx.x % ntn;
    const int NT  = K >> 6;

    const float* Ab = X + (size_t)bm * 128 * K;
    const int*   Bb = W + (size_t)bn * 128 * K;

    const int srow = t >> 4, sc4 = t & 15;

    f32x4 av[8];
    i32x4 bv[8];

    auto loadAB = [&](int kt) {
        const float* Ap = Ab + kt * 64 + sc4 * 4;
#pragma unroll
        for (int l = 0; l < 8; ++l)
            av[l] = *(const f32x4*)(Ap + (size_t)(srow + 16 * l) * K);
        const int* Bp = Bb + kt * 64 + sc4 * 4;
#pragma unroll
        for (int l = 0; l < 8; ++l)
            bv[l] = *(const i32x4*)(Bp + (size_t)(srow + 16 * l) * K);
    };

    auto writeAB = [&]() {
#pragma unroll
        for (int l = 0; l < 8; ++l) {
            const int row = srow + 16 * l;
            u32x2 pk;
            pk[0] = f2bf(av[l][0]) | (f2bf(av[l][1]) << 16);
            pk[1] = f2bf(av[l][2]) | (f2bf(av[l][3]) << 16);
            *(u32x2*)(smem + swz(row, sc4 * 8)) = pk;
        }
#pragma unroll
        for (int l = 0; l < 8; ++l) {
            const int row = srow + 16 * l;
            u32x2 pk;
            pk[0] = f2bf((float)bv[l][0]) | (f2bf((float)bv[l][1]) << 16);
            pk[1] = f2bf((float)bv[l][2]) | (f2bf((float)bv[l][3]) << 16);
            *(u32x2*)(smem + 16384 + swz(row, sc4 * 8)) = pk;
        }
    };

    f32x4 acc[4][4];
#pragma unroll
    for (int mi = 0; mi < 4; ++mi)
#pragma unroll
        for (int ni = 0; ni < 4; ++ni)
            acc[mi][ni] = (f32x4){0.f, 0.f, 0.f, 0.f};

    const int kbyte = (lane >> 4) * 16;
    const int afr   = wr * 64 + (lane & 15);
    const int bfr   = wc * 64 + (lane & 15);

    loadAB(0);

    for (int kt = 0; kt < NT; ++kt) {
        writeAB();
        __syncthreads();
        if (kt + 1 < NT) loadAB(kt + 1);
#pragma unroll
        for (int kk = 0; kk < 2; ++kk) {
            bf16x8 a[4], b[4];
#pragma unroll
            for (int mi = 0; mi < 4; ++mi)
                a[mi] = *(const bf16x8*)(smem + swz(afr + 16 * mi, kk * 64 + kbyte));
#pragma unroll
            for (int ni = 0; ni < 4; ++ni)
                b[ni] = *(const bf16x8*)(smem + 16384 + swz(bfr + 16 * ni, kk * 64 + kbyte));
#pragma unroll
            for (int mi = 0; mi < 4; ++mi)
#pragma unroll
                for (int ni = 0; ni < 4; ++ni)
                    acc[mi][ni] = __builtin_amdgcn_mfma_f32_16x16x32_bf16(
                        a[mi], b[ni], acc[mi][ni], 0, 0, 0);
        }
        __syncthreads();
    }

    const float scale = *wscale;
    const int orow0 = bm * 128 + wr * 64 + ((lane >> 4) << 2);
    const int ocol0 = bn * 128 + wc * 64 + (lane & 15);
#pragma unroll
    for (int ni = 0; ni < 4; ++ni) {
        const int col = ocol0 + 16 * ni;
        const float bb = bias[col];
#pragma unroll
        for (int mi = 0; mi < 4; ++mi) {
            const int row0 = orow0 + 16 * mi;
#pragma unroll
            for (int i = 0; i < 4; ++i)
                out[(size_t)(row0 + i) * N + col] = acc[mi][ni][i] * scale + bb;
        }
    }
}

extern "C" void kernel_launch(void* const* d_in, const int* in_sizes, int n_in,
                              void* d_out, int out_size, void* d_ws, size_t ws_size,
                              hipStream_t stream) {
    const float* x      = (const float*)d_in[0];
    const int*   w      = (const int*)d_in[1];      // int inputs arrive as int32
    const float* wscale = (const float*)d_in[2];
    const float* bias   = (const float*)d_in[3];
    float*       out    = (float*)d_out;

    const int DOUT = in_sizes[3];
    const int DIN  = in_sizes[1] / DOUT;
    const int M    = in_sizes[0] / DIN;

    const size_t xb_bytes = (size_t)M * DIN * 2;
    const size_t wb_bytes = (size_t)DOUT * DIN * 2;

    if (ws_size >= xb_bytes + wb_bytes && (M % 256) == 0 && (DOUT % 256) == 0
        && (DIN % 64) == 0 && (DIN / 64) >= 2) {
        unsigned short* xb = (unsigned short*)d_ws;
        unsigned short* wb = (unsigned short*)((char*)d_ws + xb_bytes);

        const long long nx8 = (long long)M * DIN / 8;
        const long long nw8 = (long long)DOUT * DIN / 8;
        convert_xw_kernel<<<2048, 256, 0, stream>>>(x, w, xb, wb, nx8, nx8 + nw8);

        dim3 grid((M / 256) * (DOUT / 256));
        gemm256_kernel<<<grid, 512, 0, stream>>>(xb, wb, wscale, bias, out, M, DOUT, DIN);
    } else {
        dim3 grid((M / 128) * (DOUT / 128));
        qlinear_fused_kernel<<<grid, 256, 0, stream>>>(x, w, wscale, bias, out, M, DOUT, DIN);
    }
}